// Round 1
// baseline (118.094 us; speedup 1.0000x reference)
//
#include <hip/hip_runtime.h>
#include <stdint.h>

// ---- problem constants ----
#define NPARTS 16
#define NK1    257            // rows per part
#define ROWS   4112           // 257*16 distinct embedding rows
#define MPAD   4224           // 33*128, padded GEMM M
#define VAE    768
#define ODIM   1024
#define BROWS  65536          // 4096*16 output rows

typedef __attribute__((ext_vector_type(4))) float f32x4;
typedef __attribute__((ext_vector_type(8))) short s16x8;

static __device__ __forceinline__ unsigned short f2bf(float f) {
  union { float f; unsigned u; } v; v.f = f;
  unsigned x = v.u;
  unsigned r = x + 0x7FFFu + ((x >> 16) & 1u);   // RNE
  return (unsigned short)(r >> 16);
}

static __device__ __forceinline__ void gload_lds16(const void* g, void* l) {
  __builtin_amdgcn_global_load_lds(
      (const __attribute__((address_space(1))) unsigned int*)g,
      (__attribute__((address_space(3))) unsigned int*)l, 16, 0, 0);
}

// ---------------- prep: cast emb -> bf16 (pad to MPAD rows), transpose-cast W1, W2 ----
__global__ void prep_kernel(const float* __restrict__ emb,
                            const float* __restrict__ W1,
                            const float* __restrict__ W2,
                            unsigned short* __restrict__ embB,
                            unsigned short* __restrict__ w1t,
                            unsigned short* __restrict__ w2t) {
  const int NA = MPAD * VAE / 4;       // 811008 groups of 4
  const int NB = ODIM * VAE / 4;       // 196608
  const int NC = ODIM * ODIM / 4;      // 262144
  const int TOT = NA + NB + NC;
  int stride = gridDim.x * blockDim.x;
  for (int g = blockIdx.x * blockDim.x + threadIdx.x; g < TOT; g += stride) {
    if (g < NA) {
      int i4 = g * 4;
      ushort4 o;
      if (i4 < ROWS * VAE) {
        const float4 v = *(const float4*)(emb + i4);
        o.x = f2bf(v.x); o.y = f2bf(v.y); o.z = f2bf(v.z); o.w = f2bf(v.w);
      } else {
        o.x = 0; o.y = 0; o.z = 0; o.w = 0;
      }
      *(ushort4*)(embB + i4) = o;
    } else if (g < NA + NB) {
      int j = g - NA;
      int n = j / (VAE / 4);
      int k = (j % (VAE / 4)) * 4;
      ushort4 o;
      o.x = f2bf(W1[(size_t)(k + 0) * ODIM + n]);
      o.y = f2bf(W1[(size_t)(k + 1) * ODIM + n]);
      o.z = f2bf(W1[(size_t)(k + 2) * ODIM + n]);
      o.w = f2bf(W1[(size_t)(k + 3) * ODIM + n]);
      *(ushort4*)(w1t + (size_t)n * VAE + k) = o;
    } else {
      int j = g - NA - NB;
      int n = j >> 8;
      int k = (j & 255) * 4;
      ushort4 o;
      o.x = f2bf(W2[(size_t)(k + 0) * ODIM + n]);
      o.y = f2bf(W2[(size_t)(k + 1) * ODIM + n]);
      o.z = f2bf(W2[(size_t)(k + 2) * ODIM + n]);
      o.w = f2bf(W2[(size_t)(k + 3) * ODIM + n]);
      *(ushort4*)(w2t + (size_t)n * ODIM + k) = o;
    }
  }
}

// ---------------- 128x128-tile bf16 MFMA GEMM (m97 structure: BK=32, 2-barrier loop) ----
// C[M][N] = A[M][K] * BT[N][K]^T (+ bias [+relu -> bf16 out] | [+pe -> f32 out])
template <int K, bool FUSE1>
__global__ __launch_bounds__(256) void gemm_kernel(
    const unsigned short* __restrict__ A, const unsigned short* __restrict__ BT,
    const float* __restrict__ bias, const float* __restrict__ pe,
    unsigned short* __restrict__ outB, float* __restrict__ outF) {
  __shared__ __align__(16) unsigned short As[128 * 32];
  __shared__ __align__(16) unsigned short Bs[128 * 32];

  const int tid  = threadIdx.x;
  const int lane = tid & 63;
  const int wave = tid >> 6;
  const int wr   = (wave >> 1) * 64;   // wave row offset in tile
  const int wc   = (wave & 1) * 64;    // wave col offset in tile
  const int brow = blockIdx.y * 128;
  const int bcol = blockIdx.x * 128;

  f32x4 acc[4][4];
#pragma unroll
  for (int m = 0; m < 4; ++m)
#pragma unroll
    for (int n = 0; n < 4; ++n)
#pragma unroll
      for (int r = 0; r < 4; ++r) acc[m][n][r] = 0.f;

  // staging map: thread t covers LDS bytes [t*16, t*16+16) of each 4KB chunk
  const int sr = tid >> 2;           // row within 64-row chunk
  const int sk = (tid & 3) * 8;      // k element offset (8 bf16 = 16B)
  const unsigned short* gA = A + (size_t)(brow + sr) * K + sk;
  const unsigned short* gB = BT + (size_t)(bcol + sr) * K + sk;
  unsigned short* lA = As + sr * 32 + sk;
  unsigned short* lB = Bs + sr * 32 + sk;

  const int la = lane & 15;
  const int lk = (lane >> 4) * 8;

  for (int kt = 0; kt < K; kt += 32) {
    gload_lds16(gA + kt, lA);
    gload_lds16(gA + kt + (size_t)64 * K, lA + 64 * 32);
    gload_lds16(gB + kt, lB);
    gload_lds16(gB + kt + (size_t)64 * K, lB + 64 * 32);
    __syncthreads();   // compiler drains vmcnt before barrier

    s16x8 af[4], bfr[4];
#pragma unroll
    for (int m = 0; m < 4; ++m)
      af[m] = *(const s16x8*)(As + (wr + m * 16 + la) * 32 + lk);
#pragma unroll
    for (int n = 0; n < 4; ++n)
      bfr[n] = *(const s16x8*)(Bs + (wc + n * 16 + la) * 32 + lk);
#pragma unroll
    for (int m = 0; m < 4; ++m)
#pragma unroll
      for (int n = 0; n < 4; ++n)
        acc[m][n] = __builtin_amdgcn_mfma_f32_16x16x32_bf16(af[m], bfr[n], acc[m][n], 0, 0, 0);
    __syncthreads();   // protect LDS before next stage
  }

  // epilogue: C/D layout col=lane&15, row=(lane>>4)*4+reg  [m89-verified]
#pragma unroll
  for (int m = 0; m < 4; ++m) {
    const int row0 = brow + wr + m * 16 + (lane >> 4) * 4;
#pragma unroll
    for (int n = 0; n < 4; ++n) {
      const int col = bcol + wc + n * 16 + la;
      const float bv = bias[col];
      if (FUSE1) {
#pragma unroll
        for (int r = 0; r < 4; ++r) {
          float v = acc[m][n][r] + bv;
          v = v > 0.f ? v : 0.f;
          outB[(size_t)(row0 + r) * ODIM + col] = f2bf(v);
        }
      } else {
#pragma unroll
        for (int r = 0; r < 4; ++r) {
          const int row = row0 + r;
          int p = row / NK1;
          if (p > NPARTS - 1) p = NPARTS - 1;   // padded rows: clamp (never gathered)
          outF[(size_t)row * ODIM + col] = acc[m][n][r] + bv + pe[(size_t)p * ODIM + col];
        }
      }
    }
  }
}

// ---------------- gather: out[row] = T[hash + (row&15)*257]  (pe already folded into T) ----
__global__ void gather_kernel(const int* __restrict__ hashes,
                              const float* __restrict__ T,
                              float* __restrict__ out) {
  const int row = blockIdx.x;
  const int h = hashes[row];
  const int p = row & (NPARTS - 1);
  const f32x4* src = (const f32x4*)(T + (size_t)(h + p * NK1) * ODIM);
  f32x4* dst = (f32x4*)(out + (size_t)row * ODIM);
  dst[threadIdx.x] = src[threadIdx.x];
}

// ---------------- launch ----------------
extern "C" void kernel_launch(void* const* d_in, const int* in_sizes, int n_in,
                              void* d_out, int out_size, void* d_ws, size_t ws_size,
                              hipStream_t stream) {
  const int*   hashes = (const int*)d_in[0];
  const float* emb    = (const float*)d_in[1];
  const float* W1     = (const float*)d_in[2];
  const float* b1     = (const float*)d_in[3];
  const float* W2     = (const float*)d_in[4];
  const float* b2     = (const float*)d_in[5];
  const float* pe     = (const float*)d_in[6];
  float* out = (float*)d_out;

  char* ws = (char*)d_ws;
  // ws layout (bytes):
  unsigned short* embB = (unsigned short*)(ws);                 //  4224*768*2  = 6,488,064
  unsigned short* w1t  = (unsigned short*)(ws + 6488064);       //  1024*768*2  = 1,572,864
  unsigned short* w2t  = (unsigned short*)(ws + 8060928);       //  1024*1024*2 = 2,097,152
  unsigned short* H    = (unsigned short*)(ws + 10158080);      //  4224*1024*2 = 8,650,752
  float*          T    = (float*)(ws + 18808832);               //  4224*1024*4 = 17,301,504
                                                                //  total ~36.1 MB

  prep_kernel<<<2048, 256, 0, stream>>>(emb, W1, W2, embB, w1t, w2t);

  dim3 gg(ODIM / 128, MPAD / 128);  // (8, 33)
  gemm_kernel<VAE, true><<<gg, 256, 0, stream>>>(embB, w1t, b1, nullptr, H, nullptr);
  gemm_kernel<ODIM, false><<<gg, 256, 0, stream>>>(H, w2t, b2, pe, nullptr, T);

  gather_kernel<<<BROWS, 256, 0, stream>>>(hashes, T, out);
}

// Round 2
// 101.702 us; speedup vs baseline: 1.1612x; 1.1612x over previous
//
#include <hip/hip_runtime.h>
#include <stdint.h>

// ---- problem constants ----
#define NPARTS 16
#define NK1    257            // rows per part
#define ROWS   4112           // 257*16 distinct embedding rows
#define MPAD   4224           // 66*64, padded GEMM M
#define VAE    768
#define ODIM   1024
#define BROWS  65536          // 4096*16 output rows

typedef __attribute__((ext_vector_type(4))) float f32x4;
typedef __attribute__((ext_vector_type(8))) short s16x8;

static __device__ __forceinline__ unsigned short f2bf(float f) {
  union { float f; unsigned u; } v; v.f = f;
  unsigned x = v.u;
  unsigned r = x + 0x7FFFu + ((x >> 16) & 1u);   // RNE
  return (unsigned short)(r >> 16);
}

static __device__ __forceinline__ void gload_lds16(const void* g, void* l) {
  __builtin_amdgcn_global_load_lds(
      (const __attribute__((address_space(1))) unsigned int*)g,
      (__attribute__((address_space(3))) unsigned int*)l, 16, 0, 0);
}

// ---------------- prep: cast emb -> bf16 (pad to MPAD rows); LDS-tiled transpose-cast W1,W2 ----
// grid: [0,1024) grid-stride emb cast; [1024,1792) W1 32x32 tiles; [1792,2816) W2 tiles
#define EMB_BLOCKS 1024
__global__ __launch_bounds__(256) void prep_kernel(
    const float* __restrict__ emb, const float* __restrict__ W1,
    const float* __restrict__ W2, unsigned short* __restrict__ embB,
    unsigned short* __restrict__ w1t, unsigned short* __restrict__ w2t) {
  __shared__ unsigned short tile[32][33];
  const int tid = threadIdx.x;
  const int bid = blockIdx.x;
  if (bid < EMB_BLOCKS) {
    const int NQ = MPAD * VAE / 4;   // 811008 quads
    for (int g = bid * 256 + tid; g < NQ; g += EMB_BLOCKS * 256) {
      const int i4 = g * 4;
      ushort4 o;
      if (i4 < ROWS * VAE) {
        const float4 v = *(const float4*)(emb + i4);
        o.x = f2bf(v.x); o.y = f2bf(v.y); o.z = f2bf(v.z); o.w = f2bf(v.w);
      } else {
        o.x = 0; o.y = 0; o.z = 0; o.w = 0;
      }
      *(ushort4*)(embB + i4) = o;
    }
  } else {
    int tb = bid - EMB_BLOCKS;
    const float* W; unsigned short* outp; int KD;
    if (tb < 768) { W = W1; outp = w1t; KD = VAE; }          // 24 k-tiles x 32 n-tiles
    else          { tb -= 768; W = W2; outp = w2t; KD = ODIM; }
    const int nkt = KD / 32;
    const int tk = (tb % nkt) * 32;
    const int tn = (tb / nkt) * 32;
    // read 32 (k) x 32 (n) tile, coalesced along n
    const int r  = tid >> 3;           // k-local
    const int c4 = (tid & 7) * 4;      // n-local
    const float4 v = *(const float4*)(W + (size_t)(tk + r) * ODIM + tn + c4);
    tile[r][c4 + 0] = f2bf(v.x);
    tile[r][c4 + 1] = f2bf(v.y);
    tile[r][c4 + 2] = f2bf(v.z);
    tile[r][c4 + 3] = f2bf(v.w);
    __syncthreads();
    // write transposed: out[n][k], coalesced along k (ushort4)
    ushort4 o;
    o.x = tile[c4 + 0][r];
    o.y = tile[c4 + 1][r];
    o.z = tile[c4 + 2][r];
    o.w = tile[c4 + 3][r];
    *(ushort4*)(outp + (size_t)(tn + r) * KD + tk + c4) = o;
  }
}

// ---------------- 64x128-tile bf16 MFMA GEMM (BK=32, 2-barrier loop, 2 blocks/CU) ----
// C[M][N] = A[M][K] * BT[N][K]^T  (+bias,relu -> bf16 | +bias+pe -> f32)
template <int K, bool FUSE1>
__global__ __launch_bounds__(256) void gemm_kernel(
    const unsigned short* __restrict__ A, const unsigned short* __restrict__ BT,
    const float* __restrict__ bias, const float* __restrict__ pe,
    unsigned short* __restrict__ outB, float* __restrict__ outF) {
  __shared__ __align__(16) unsigned short As[64 * 32];    // 4KB
  __shared__ __align__(16) unsigned short Bs[128 * 32];   // 8KB

  const int tid  = threadIdx.x;
  const int lane = tid & 63;
  const int wave = tid >> 6;
  const int wc   = wave * 32;          // wave col offset in 128-wide tile
  const int brow = blockIdx.y * 64;
  const int bcol = blockIdx.x * 128;

  f32x4 acc[4][2];
#pragma unroll
  for (int m = 0; m < 4; ++m)
#pragma unroll
    for (int n = 0; n < 2; ++n)
#pragma unroll
      for (int r = 0; r < 4; ++r) acc[m][n][r] = 0.f;

  // staging: thread t covers 16B of each 4KB (64-row) chunk
  const int sr = tid >> 2;             // row in 64-row chunk
  const int sk = (tid & 3) * 8;        // k elem offset
  const unsigned short* gA = A + (size_t)(brow + sr) * K + sk;
  const unsigned short* gB = BT + (size_t)(bcol + sr) * K + sk;
  unsigned short* lA = As + sr * 32 + sk;
  unsigned short* lB = Bs + sr * 32 + sk;

  const int la = lane & 15;
  const int lk = (lane >> 4) * 8;

  for (int kt = 0; kt < K; kt += 32) {
    gload_lds16(gA + kt, lA);
    gload_lds16(gB + kt, lB);
    gload_lds16(gB + kt + (size_t)64 * K, lB + 64 * 32);
    __syncthreads();

    s16x8 af[4], bfr[2];
#pragma unroll
    for (int m = 0; m < 4; ++m)
      af[m] = *(const s16x8*)(As + (m * 16 + la) * 32 + lk);
#pragma unroll
    for (int n = 0; n < 2; ++n)
      bfr[n] = *(const s16x8*)(Bs + (wc + n * 16 + la) * 32 + lk);
#pragma unroll
    for (int m = 0; m < 4; ++m)
#pragma unroll
      for (int n = 0; n < 2; ++n)
        acc[m][n] = __builtin_amdgcn_mfma_f32_16x16x32_bf16(af[m], bfr[n], acc[m][n], 0, 0, 0);
    __syncthreads();
  }

  // epilogue: C/D layout col=lane&15, row=(lane>>4)*4+reg  [m89-verified]
#pragma unroll
  for (int m = 0; m < 4; ++m) {
    const int row0 = brow + m * 16 + (lane >> 4) * 4;
#pragma unroll
    for (int n = 0; n < 2; ++n) {
      const int col = bcol + wc + n * 16 + la;
      const float bv = bias[col];
      if (FUSE1) {
#pragma unroll
        for (int r = 0; r < 4; ++r) {
          float v = acc[m][n][r] + bv;
          v = v > 0.f ? v : 0.f;
          outB[(size_t)(row0 + r) * ODIM + col] = f2bf(v);
        }
      } else {
#pragma unroll
        for (int r = 0; r < 4; ++r) {
          const int row = row0 + r;
          int p = row / NK1;
          if (p > NPARTS - 1) p = NPARTS - 1;   // padded rows: never gathered
          outF[(size_t)row * ODIM + col] = acc[m][n][r] + bv + pe[(size_t)p * ODIM + col];
        }
      }
    }
  }
}

// ---------------- gather: out[row] = T[hash + (row&15)*257]  (bias+pe folded into T) ----
// wave-per-row grid-stride; nontemporal stores keep T resident in L2
__global__ __launch_bounds__(256) void gather_kernel(const int* __restrict__ hashes,
                                                     const float* __restrict__ T,
                                                     float* __restrict__ out) {
  const int wid  = (blockIdx.x * blockDim.x + threadIdx.x) >> 6;
  const int lane = threadIdx.x & 63;
  const int nw   = (gridDim.x * blockDim.x) >> 6;
  for (int row = wid; row < BROWS; row += nw) {
    const int h = __builtin_amdgcn_readfirstlane(hashes[row]);
    const int p = row & (NPARTS - 1);
    const f32x4* __restrict__ src = (const f32x4*)(T + (size_t)(h + p * NK1) * ODIM);
    f32x4* __restrict__ dst = (f32x4*)(out + (size_t)row * ODIM);
#pragma unroll
    for (int j = 0; j < 4; ++j) {
      f32x4 v = src[lane + j * 64];
      __builtin_nontemporal_store(v, dst + lane + j * 64);
    }
  }
}

// ---------------- launch ----------------
extern "C" void kernel_launch(void* const* d_in, const int* in_sizes, int n_in,
                              void* d_out, int out_size, void* d_ws, size_t ws_size,
                              hipStream_t stream) {
  const int*   hashes = (const int*)d_in[0];
  const float* emb    = (const float*)d_in[1];
  const float* W1     = (const float*)d_in[2];
  const float* b1     = (const float*)d_in[3];
  const float* W2     = (const float*)d_in[4];
  const float* b2     = (const float*)d_in[5];
  const float* pe     = (const float*)d_in[6];
  float* out = (float*)d_out;

  char* ws = (char*)d_ws;
  unsigned short* embB = (unsigned short*)(ws);                 //  4224*768*2  = 6,488,064
  unsigned short* w1t  = (unsigned short*)(ws + 6488064);       //  1024*768*2  = 1,572,864
  unsigned short* w2t  = (unsigned short*)(ws + 8060928);       //  1024*1024*2 = 2,097,152
  unsigned short* H    = (unsigned short*)(ws + 10158080);      //  4224*1024*2 = 8,650,752
  float*          T    = (float*)(ws + 18808832);               //  4224*1024*4 = 17,301,504

  prep_kernel<<<EMB_BLOCKS + 768 + 1024, 256, 0, stream>>>(emb, W1, W2, embB, w1t, w2t);

  dim3 gg(ODIM / 128, MPAD / 64);  // (8, 66) -> 528 blocks, ~2/CU
  gemm_kernel<VAE, true><<<gg, 256, 0, stream>>>(embB, w1t, b1, nullptr, H, nullptr);
  gemm_kernel<ODIM, false><<<gg, 256, 0, stream>>>(H, w2t, b2, pe, nullptr, T);

  gather_kernel<<<1024, 256, 0, stream>>>(hashes, T, out);
}

// Round 3
// 93.996 us; speedup vs baseline: 1.2564x; 1.0820x over previous
//
#include <hip/hip_runtime.h>
#include <stdint.h>

// ---- problem constants ----
#define NPARTS 16
#define NK1    257            // rows per part
#define ROWS   4112           // 257*16 distinct embedding rows
#define MPAD   4224           // 66*64, padded GEMM M
#define VAE    768
#define ODIM   1024
#define BROWS  65536          // 4096*16 output rows

typedef __attribute__((ext_vector_type(4))) float f32x4;
typedef __attribute__((ext_vector_type(8))) short s16x8;

static __device__ __forceinline__ unsigned short f2bf(float f) {
  union { float f; unsigned u; } v; v.f = f;
  unsigned x = v.u;
  unsigned r = x + 0x7FFFu + ((x >> 16) & 1u);   // RNE
  return (unsigned short)(r >> 16);
}

static __device__ __forceinline__ void gload_lds16(const void* g, void* l) {
  __builtin_amdgcn_global_load_lds(
      (const __attribute__((address_space(1))) unsigned int*)g,
      (__attribute__((address_space(3))) unsigned int*)l, 16, 0, 0);
}

// ---------------- prep: cast emb -> bf16 (pad to MPAD rows); transpose-cast W1 ----
// grid: [0,1024) grid-stride emb cast; [1024,1792) W1 32x32 tiles
#define EMB_BLOCKS 1024
__global__ __launch_bounds__(256) void prep_kernel(
    const float* __restrict__ emb, const float* __restrict__ W1,
    unsigned short* __restrict__ embB, unsigned short* __restrict__ w1t) {
  __shared__ unsigned short tile[32][33];
  const int tid = threadIdx.x;
  const int bid = blockIdx.x;
  if (bid < EMB_BLOCKS) {
    const int NQ = MPAD * VAE / 4;   // 811008 quads
    for (int g = bid * 256 + tid; g < NQ; g += EMB_BLOCKS * 256) {
      const int i4 = g * 4;
      ushort4 o;
      if (i4 < ROWS * VAE) {
        const float4 v = *(const float4*)(emb + i4);
        o.x = f2bf(v.x); o.y = f2bf(v.y); o.z = f2bf(v.z); o.w = f2bf(v.w);
      } else {
        o.x = 0; o.y = 0; o.z = 0; o.w = 0;
      }
      *(ushort4*)(embB + i4) = o;
    }
  } else {
    const int tb = bid - EMB_BLOCKS;         // 768 tiles: 24 k-tiles x 32 n-tiles
    const int nkt = VAE / 32;
    const int tk = (tb % nkt) * 32;
    const int tn = (tb / nkt) * 32;
    const int r  = tid >> 3;                 // k-local
    const int c4 = (tid & 7) * 4;            // n-local
    const float4 v = *(const float4*)(W1 + (size_t)(tk + r) * ODIM + tn + c4);
    tile[r][c4 + 0] = f2bf(v.x);
    tile[r][c4 + 1] = f2bf(v.y);
    tile[r][c4 + 2] = f2bf(v.z);
    tile[r][c4 + 3] = f2bf(v.w);
    __syncthreads();
    ushort4 o;
    o.x = tile[c4 + 0][r];
    o.y = tile[c4 + 1][r];
    o.z = tile[c4 + 2][r];
    o.w = tile[c4 + 3][r];
    *(ushort4*)(w1t + (size_t)(tn + r) * VAE + tk + c4) = o;
  }
}

// ---------------- 64x128-tile bf16 MFMA GEMM ----------------
// 2-phase dbuf, BK=64, XOR-swizzled staging (swizzled global src + linear LDS
// dest [m104/m108], swizzled ds_read [rule #21]).
// MODE 0: out = relu(acc+bias) -> bf16   (GEMM1 -> H)
// MODE 2: out = acc+bias+pe[row/257] -> f32  (GEMM2 -> T)
// DO_W2T: blockIdx.z==1 blocks instead transpose-cast W2 -> w2dst (overlap).
template <int K, int MODE, bool DO_W2T>
__global__ __launch_bounds__(256) void gemm_kernel(
    const unsigned short* __restrict__ A, const unsigned short* __restrict__ BT,
    const float* __restrict__ bias, const float* __restrict__ pe,
    unsigned short* __restrict__ outB, float* __restrict__ outF,
    const float* __restrict__ W2src, unsigned short* __restrict__ w2dst) {
  __shared__ __align__(16) unsigned short smem[2 * 12288];   // 2 x (A 4K + B 8K) us
  const int tid = threadIdx.x;

  if (DO_W2T && blockIdx.z == 1) {
    // transpose-cast W2[k][n] -> w2dst[n][k], 32k x 128n tiles (256 blocks)
    if (blockIdx.y >= 32) return;
    unsigned short (*tile)[132] = (unsigned short (*)[132])smem;
    const int tk = blockIdx.y * 32, tn = blockIdx.x * 128;
#pragma unroll
    for (int p = 0; p < 4; ++p) {
      const int row = (tid >> 5) + p * 8, c4 = (tid & 31) * 4;
      const float4 v = *(const float4*)(W2src + (size_t)(tk + row) * ODIM + tn + c4);
      tile[row][c4 + 0] = f2bf(v.x); tile[row][c4 + 1] = f2bf(v.y);
      tile[row][c4 + 2] = f2bf(v.z); tile[row][c4 + 3] = f2bf(v.w);
    }
    __syncthreads();
#pragma unroll
    for (int q = 0; q < 4; ++q) {
      const int n = (tid >> 3) + q * 32, k4 = (tid & 7) * 4;
      ushort4 o;
      o.x = tile[k4 + 0][n]; o.y = tile[k4 + 1][n];
      o.z = tile[k4 + 2][n]; o.w = tile[k4 + 3][n];
      *(ushort4*)(w2dst + (size_t)(tn + n) * ODIM + tk + k4) = o;
    }
    return;
  }

  const int lane = tid & 63;
  const int wave = tid >> 6;
  const int wc   = wave * 32;          // wave col offset in 128-wide tile
  const int brow = blockIdx.y * 64;
  const int bcol = blockIdx.x * 128;
  const int la   = lane & 15;
  const int hi   = lane >> 4;          // 0..3

  f32x4 acc[4][2];
#pragma unroll
  for (int m = 0; m < 4; ++m)
#pragma unroll
    for (int n = 0; n < 2; ++n)
#pragma unroll
      for (int r = 0; r < 4; ++r) acc[m][n][r] = 0.f;

  // staging: thread t covers LDS bytes [t*16, t*16+16) of each 4KB (32-row) chunk.
  // Global k-block is XOR-swizzled so that LDS slot (row, kb) holds k-block
  // kb ^ (row & 7) -> ds_read_b128 at 128B row stride becomes conflict-free.
  const int srow = tid >> 3;                       // 0..31
  const int skb  = (tid & 7) ^ (srow & 7);         // swizzled k-block
  const unsigned short* gA = A + (size_t)(brow + srow) * K + skb * 8;
  const unsigned short* gB = BT + (size_t)(bcol + srow) * K + skb * 8;

#define STAGE(b, kt)                                              \
  {                                                               \
    unsigned short* la_ = smem + (b) * 12288 + tid * 8;           \
    unsigned short* lb_ = la_ + 4096;                             \
    gload_lds16(gA + (kt), la_);                                  \
    gload_lds16(gA + (kt) + 32 * K, la_ + 2048);                  \
    gload_lds16(gB + (kt), lb_);                                  \
    gload_lds16(gB + (kt) + 32 * K, lb_ + 2048);                  \
    gload_lds16(gB + (kt) + 64 * K, lb_ + 4096);                  \
    gload_lds16(gB + (kt) + 96 * K, lb_ + 6144);                  \
  }

  STAGE(0, 0);
  asm volatile("s_waitcnt vmcnt(0)" ::: "memory");
  __builtin_amdgcn_s_barrier();

  const int NT = K / 64;
  for (int t = 0; t < NT; ++t) {
    const int cur = t & 1;
    if (t + 1 < NT) STAGE(cur ^ 1, (t + 1) * 64);   // prefetch overlaps compute

    const unsigned short* As = smem + cur * 12288;
    const unsigned short* Bs = As + 4096;
    s16x8 af[4][2], bf[2][2];
#pragma unroll
    for (int m = 0; m < 4; ++m)
#pragma unroll
      for (int ks = 0; ks < 2; ++ks)
        af[m][ks] = *(const s16x8*)(As + (m * 16 + la) * 64 +
                                    (((ks * 4 + hi) ^ (la & 7)) * 8));
#pragma unroll
    for (int n = 0; n < 2; ++n)
#pragma unroll
      for (int ks = 0; ks < 2; ++ks)
        bf[n][ks] = *(const s16x8*)(Bs + (wc + n * 16 + la) * 64 +
                                    (((ks * 4 + hi) ^ (la & 7)) * 8));
#pragma unroll
    for (int m = 0; m < 4; ++m)
#pragma unroll
      for (int n = 0; n < 2; ++n)
#pragma unroll
        for (int ks = 0; ks < 2; ++ks)
          acc[m][n] = __builtin_amdgcn_mfma_f32_16x16x32_bf16(af[m][ks], bf[n][ks],
                                                              acc[m][n], 0, 0, 0);
    // one counted drain + raw barrier per K-tile (prefetch loads complete here,
    // having overlapped with the ds_read+MFMA above)
    asm volatile("s_waitcnt vmcnt(0)" ::: "memory");
    __builtin_amdgcn_sched_barrier(0);
    __builtin_amdgcn_s_barrier();
  }
#undef STAGE

  // epilogue: C/D layout col=lane&15, row=(lane>>4)*4+reg  [m89-verified]
#pragma unroll
  for (int m = 0; m < 4; ++m) {
    const int row0 = brow + m * 16 + hi * 4;
#pragma unroll
    for (int n = 0; n < 2; ++n) {
      const int col = bcol + wc + n * 16 + la;
      const float bv = bias[col];
      if (MODE == 0) {
#pragma unroll
        for (int r = 0; r < 4; ++r) {
          float v = acc[m][n][r] + bv;
          v = v > 0.f ? v : 0.f;
          outB[(size_t)(row0 + r) * ODIM + col] = f2bf(v);
        }
      } else {
#pragma unroll
        for (int r = 0; r < 4; ++r) {
          const int row = row0 + r;
          int p = row / NK1;
          if (p > NPARTS - 1) p = NPARTS - 1;   // padded rows: never gathered
          outF[(size_t)row * ODIM + col] = acc[m][n][r] + bv + pe[(size_t)p * ODIM + col];
        }
      }
    }
  }
}

// ---------------- gather: out[row] = T[hash + (row&15)*257]  (bias+pe folded into T) ----
__global__ __launch_bounds__(256) void gather_kernel(const int* __restrict__ hashes,
                                                     const float* __restrict__ T,
                                                     float* __restrict__ out) {
  const int wid  = (blockIdx.x * blockDim.x + threadIdx.x) >> 6;
  const int lane = threadIdx.x & 63;
  const int nw   = (gridDim.x * blockDim.x) >> 6;
  for (int row = wid; row < BROWS; row += nw) {
    const int h = __builtin_amdgcn_readfirstlane(hashes[row]);
    const int p = row & (NPARTS - 1);
    const f32x4* __restrict__ src = (const f32x4*)(T + (size_t)(h + p * NK1) * ODIM);
    f32x4* __restrict__ dst = (f32x4*)(out + (size_t)row * ODIM);
#pragma unroll
    for (int j = 0; j < 4; ++j) {
      f32x4 v = src[lane + j * 64];
      __builtin_nontemporal_store(v, dst + lane + j * 64);
    }
  }
}

// ---------------- launch ----------------
extern "C" void kernel_launch(void* const* d_in, const int* in_sizes, int n_in,
                              void* d_out, int out_size, void* d_ws, size_t ws_size,
                              hipStream_t stream) {
  const int*   hashes = (const int*)d_in[0];
  const float* emb    = (const float*)d_in[1];
  const float* W1     = (const float*)d_in[2];
  const float* b1     = (const float*)d_in[3];
  const float* W2     = (const float*)d_in[4];
  const float* b2     = (const float*)d_in[5];
  const float* pe     = (const float*)d_in[6];
  float* out = (float*)d_out;

  char* ws = (char*)d_ws;
  unsigned short* embB = (unsigned short*)(ws);                 //  4224*768*2  = 6,488,064
  unsigned short* w1t  = (unsigned short*)(ws + 6488064);       //  1024*768*2  = 1,572,864
  unsigned short* w2t  = (unsigned short*)(ws + 8060928);       //  1024*1024*2 = 2,097,152
  unsigned short* H    = (unsigned short*)(ws + 10158080);      //  4224*1024*2 = 8,650,752
  float*          T    = (float*)(ws + 18808832);               //  4224*1024*4 = 17,301,504

  prep_kernel<<<EMB_BLOCKS + 768, 256, 0, stream>>>(emb, W1, embB, w1t);

  // GEMM1 (z=0: 528 gemm blocks) + W2 transpose overlapped (z=1: 256 blocks)
  gemm_kernel<VAE, 0, true><<<dim3(8, 66, 2), 256, 0, stream>>>(
      embB, w1t, b1, nullptr, H, nullptr, W2, w2t);

  gemm_kernel<ODIM, 2, false><<<dim3(8, 66, 1), 256, 0, stream>>>(
      H, w2t, b2, pe, nullptr, T, nullptr, nullptr);

  gather_kernel<<<1024, 256, 0, stream>>>(hashes, T, out);
}